// Round 6
// baseline (698.094 us; speedup 1.0000x reference)
//
#include <hip/hip_runtime.h>
#include <hip/hip_bf16.h>

#define BB 8
#define LL 1024
#define TT 10
#define TILE 64
#define NTILE 16
#define NOFF 120                     // off-diag pairs per batch (I<J)
#define NOFFT (BB*NOFF)              // 960
#define NBLK (NOFFT + BB*NTILE)      // 1088 total; capacity >= 5/CU * 256 = 1280
#define S_CONST 2.1972245773362196f

typedef __hip_bfloat16 bf16;

static __device__ __forceinline__ float sigm(float v) {
    return 1.0f / (1.0f + __expf(-v));
}
static __device__ __forceinline__ unsigned short f2bf(float v) {
    bf16 h = __float2bfloat16(v);   // RNE, same rounding as round-1 (passing)
    unsigned short b; __builtin_memcpy(&b, &h, 2); return b;
}
static __device__ __forceinline__ float lo2f(unsigned int v) { return __uint_as_float(v << 16); }
static __device__ __forceinline__ float hi2f(unsigned int v) { return __uint_as_float(v & 0xffff0000u); }
static __device__ __forceinline__ unsigned int pk2(float uu, float ah) {
    return (unsigned int)f2bf(uu) | ((unsigned int)f2bf(ah) << 16);
}

// raw barrier: LDS ordering only (lgkmcnt), NO vmcnt drain — global stores stay in flight
#define RAWBAR() do { asm volatile("s_waitcnt lgkmcnt(0)" ::: "memory"); \
                      __builtin_amdgcn_s_barrier(); } while (0)

// fine-grained dependency counters: done[(t*128 + b*16 + tile)*16], 16 producers per tile
static __device__ __forceinline__ void wait_done(const unsigned int* dcnt) {
    for (int it = 0; it < (1 << 20); ++it) {   // backstop only
        if (__hip_atomic_load(dcnt, __ATOMIC_RELAXED, __HIP_MEMORY_SCOPE_AGENT) >= 16u)
            break;
        __builtin_amdgcn_s_sleep(4);
    }
}
static __device__ __forceinline__ void add_done(unsigned int* done, int t, int b, int tile) {
    __hip_atomic_fetch_add(&done[((size_t)t*128 + b*16 + tile)*16], 1u,
                           __ATOMIC_RELAXED, __HIP_MEMORY_SCOPE_AGENT);
}

// h = relu(W1 f + b1); out = relu(W2 h + b2)
static __device__ __forceinline__ float mlp3(float f0, float f1, float f2, const float* w) {
    float h0 = fmaxf(w[0]*f0 + w[1]*f1 + w[2]*f2 + w[9],  0.0f);
    float h1 = fmaxf(w[3]*f0 + w[4]*f1 + w[5]*f2 + w[10], 0.0f);
    float h2 = fmaxf(w[6]*f0 + w[7]*f1 + w[8]*f2 + w[11], 0.0f);
    return fmaxf(w[12]*h0 + w[13]*h1 + w[14]*h2 + w[15], 0.0f);
}
static __device__ __forceinline__ float ahnew_calc(float ah, float grad, float uuv, const float* w) {
    float va = mlp3(ah, grad, uuv, w);
    float vr = mlp3(ah, grad, uuv, w + 16);
    float v = fmaxf(fabsf(va) - vr, 0.0f);
    return fminf(v, 1.0f);
}

#define LOAD_W(tt) do { if (tid < 32) { int _t = (tt); float v; \
    if      (tid <  9) v = aW1[_t*9 + tid]; \
    else if (tid < 12) v = ab1[_t*3 + (tid-9)]; \
    else if (tid < 15) v = aW2[_t*3 + (tid-12)]; \
    else if (tid < 16) v = ab2[_t]; \
    else if (tid < 25) v = rW1[_t*9 + (tid-16)]; \
    else if (tid < 28) v = rb1[_t*3 + (tid-25)]; \
    else if (tid < 31) v = rW2[_t*3 + (tid-28)]; \
    else               v = rb2[_t]; \
    w[tid] = v; } } while (0)

#define LAM_UPDATE(rsv) do { \
    float lg = fmaxf((rsv) - 1.0f, 0.0f); \
    if (t == 0) lam = lg; \
    else { int o = t - 1; \
        float h0 = fmaxf(lW1[o*6+0]*lam + lW1[o*6+1]*lg + lb1[o*3+0], 0.0f); \
        float h1 = fmaxf(lW1[o*6+2]*lam + lW1[o*6+3]*lg + lb1[o*3+1], 0.0f); \
        float h2 = fmaxf(lW1[o*6+4]*lam + lW1[o*6+5]*lg + lb1[o*3+2], 0.0f); \
        lam = fmaxf(lW2[o*3+0]*h0 + lW2[o*3+1]*h1 + lW2[o*3+2]*h2 + lb2[o], 0.0f); } \
    } while (0)

__global__ __launch_bounds__(256, 5) void k_main(
        const float* __restrict__ u, const float* __restrict__ x,
        float* __restrict__ rs, unsigned int* __restrict__ done,
        float* __restrict__ out,
        const float* __restrict__ aW1, const float* __restrict__ ab1,
        const float* __restrict__ aW2, const float* __restrict__ ab2,
        const float* __restrict__ rW1, const float* __restrict__ rb1,
        const float* __restrict__ rW2, const float* __restrict__ rb2,
        const float* __restrict__ lW1, const float* __restrict__ lb1,
        const float* __restrict__ lW2, const float* __restrict__ lb2) {
    // LDS: 16640(buf) + 1024(xIl) + 4*256(ls/rs) + 128(w) = 18816 B
    __shared__ unsigned int bufU[TILE * 65];   // staging: init transpose (u32) / a_val (f32)
    __shared__ float xIl[4 * TILE];
    __shared__ float lsI[TILE], lsJ[TILE];
    __shared__ float rsIb[TILE], rsJb[TILE];
    __shared__ float w[32];
    float* buff = (float*)bufU;

    int gid = blockIdx.x, tid = threadIdx.x;
    int c = tid & 63, rg = tid >> 6;
    float lam = 0.0f;

    if (gid < NOFFT) {
        // ================= off-diagonal pair: state in 32 VGPRs =================
        int b = gid / NOFF, po = gid % NOFF;
        int i = 0; while (po >= NTILE - 1 - i) { po -= NTILE - 1 - i; i++; }
        int I = i, J = i + 1 + po;
        int Ib = I * TILE, Jb = J * TILE;

        float4 xc4 = ((const float4*)x)[(size_t)b*LL + Jb + c];
        float bu_c = xc4.y, bg_c = xc4.w, s1_c = xc4.x + xc4.w, s2_c = xc4.z + xc4.y;
        { int row = tid >> 2, k2 = tid & 3;
          xIl[k2*TILE + row] = x[((size_t)b*LL + Ib + row)*4 + k2]; }

        unsigned int vIJ[16], vJI[16];     // packed (lo=uu, hi=ahat); vJI holds JI-transposed slots
        size_t ubIJ = ((size_t)b*LL + Ib)*LL + Jb;
        size_t ubJI = ((size_t)b*LL + Jb)*LL + Ib;
        #pragma unroll
        for (int k = 0; k < 16; k++) {
            int r = rg + 4*k;
            float uv  = u[ubIJ + (size_t)r*LL + c];
            float uuv = sigm(2.0f*(uv - S_CONST))*uv;
            float ah  = sigm(uuv)*sigm(2.0f*(uuv - S_CONST));
            vIJ[k] = pk2(uuv, ah);
            uv  = u[ubJI + (size_t)r*LL + c];
            uuv = sigm(2.0f*(uv - S_CONST))*uv;
            ah  = sigm(uuv)*sigm(2.0f*(uuv - S_CONST));
            bufU[r*65 + c] = pk2(uuv, ah);           // stage JI tile for transpose
        }
        if (tid < 64) rsIb[tid] = 0.0f; else if (tid < 128) rsJb[tid-64] = 0.0f;
        RAWBAR();
        #pragma unroll
        for (int k = 0; k < 16; k++) vJI[k] = bufU[c*65 + (rg + 4*k)];   // own transposed slot
        RAWBAR();                                     // before buf reuse as f32 stage

        // ---- a0 rowsums ----
        {
            float rsJacc = 0.0f;
            #pragma unroll
            for (int k = 0; k < 16; k++) {
                int r = rg + 4*k;
                float ah_ij = hi2f(vIJ[k]), ah_ji = hi2f(vJI[k]);
                float m = xIl[0*TILE+r]*bu_c + xIl[2*TILE+r]*bg_c
                        + xIl[1*TILE+r]*s1_c + xIl[3*TILE+r]*s2_c;
                float a0 = 0.5f*(ah_ij*ah_ij + ah_ji*ah_ji)*m;
                buff[r*65 + c] = a0;
                rsJacc += a0;
            }
            atomicAdd(&rsJb[c], rsJacc);
            RAWBAR();
            { int jj = tid & 63, cc0 = tid >> 6;
              float part = 0.0f;
              #pragma unroll
              for (int s = 0; s < 16; s++) part += buff[jj*65 + (cc0*16 + s)];
              atomicAdd(&rsIb[jj], part); }
            RAWBAR();
            if (tid < 64) atomicAdd(&rs[b*LL + Ib + tid], rsIb[tid]);
            else if (tid < 128) atomicAdd(&rs[b*LL + Jb + (tid-64)], rsJb[tid-64]);
            if (tid < 128) {
                asm volatile("s_waitcnt vmcnt(0)" ::: "memory");
                if (tid == 0)  add_done(done, 0, b, I);
                if (tid == 64) add_done(done, 0, b, J);
            }
        }

        // ---- time loop; state entirely in registers ----
        for (int t = 0; t < TT; t++) {
            LOAD_W(t);
            if (tid == 0)  wait_done(&done[((size_t)t*128 + b*16 + I)*16]);
            if (tid == 64) wait_done(&done[((size_t)t*128 + b*16 + J)*16]);
            RAWBAR();
            const float* rs_cur = rs + (size_t)t*BB*LL;
            if (tid < 128) {
                int row = (tid < 64) ? (Ib + tid) : (Jb + tid - 64);
                float rsv = __hip_atomic_load(&rs_cur[b*LL + row], __ATOMIC_RELAXED, __HIP_MEMORY_SCOPE_AGENT);
                LAM_UPDATE(rsv);
                float lsv = lam * sigm(2.0f*(rsv - 1.0f));
                if (tid < 64) { lsI[tid] = lsv; rsIb[tid] = 0.0f; }
                else          { lsJ[tid-64] = lsv; rsJb[tid-64] = 0.0f; }
            }
            RAWBAR();

            size_t outBase = (((size_t)t*BB + b)*LL)*LL;
            bool last = (t == TT-1);
            float rsJacc = 0.0f;
            #pragma unroll
            for (int k = 0; k < 16; k++) {
                int r = rg + 4*k;
                unsigned int vA = vIJ[k], vB = vJI[k];
                float uu_ij = lo2f(vA), ah_ij = hi2f(vA);
                float uu_ji = lo2f(vB), ah_ji = hi2f(vB);
                float m = xIl[0*TILE+r]*bu_c + xIl[2*TILE+r]*bg_c
                        + xIl[1*TILE+r]*s1_c + xIl[3*TILE+r]*s2_c;
                float gsum = -0.5f*(uu_ij + uu_ji) + lsI[r] + lsJ[c];
                float an_ij = ahnew_calc(ah_ij, ah_ij*m*gsum, uu_ij, w);
                float an_ji = ahnew_calc(ah_ji, ah_ji*m*gsum, uu_ji, w);
                float a_val = 0.5f*(an_ij*an_ij + an_ji*an_ji)*m;
                vIJ[k] = ((unsigned int)f2bf(an_ij) << 16) | (vA & 0xffffu);
                vJI[k] = ((unsigned int)f2bf(an_ji) << 16) | (vB & 0xffffu);
                __builtin_nontemporal_store(a_val, &out[outBase + (size_t)(Ib+r)*LL + (Jb+c)]);
                buff[r*65 + c] = a_val;
                rsJacc += a_val;
            }
            if (!last) atomicAdd(&rsJb[c], rsJacc);
            RAWBAR();
            // one-pass drain: JI writeback (coalesced 256B/wave) + rsI column sums
            { int jj = tid & 63, cc0 = tid >> 6;
              float part = 0.0f;
              #pragma unroll
              for (int s = 0; s < 16; s++) {
                  int cc = cc0*16 + s;
                  float v = buff[jj*65 + cc];
                  __builtin_nontemporal_store(v, &out[outBase + (size_t)(Jb+cc)*LL + (Ib + jj)]);
                  part += v;
              }
              if (!last) atomicAdd(&rsIb[jj], part); }
            if (!last) {
                RAWBAR();
                float* rs_next = rs + (size_t)(t+1)*BB*LL;
                if (tid < 128) {
                    if (tid < 64) atomicAdd(&rs_next[b*LL + Ib + tid], rsIb[tid]);
                    else          atomicAdd(&rs_next[b*LL + Jb + (tid-64)], rsJb[tid-64]);
                    asm volatile("s_waitcnt vmcnt(0)" ::: "memory");
                    if (tid == 0)  add_done(done, t+1, b, I);
                    if (tid == 64) add_done(done, t+1, b, J);
                }
            }
        }
    } else {
        // ================= diagonal tile (one per block): state in 32 VGPRs =================
        int d = gid - NOFFT;            // 0..127
        int b = d >> 4, tI = d & 15;
        int Ab = tI * TILE;

        float4 xc4 = ((const float4*)x)[(size_t)b*LL + Ab + c];
        float ac = xc4.x, uc = xc4.y, cc_ = xc4.z, gc = xc4.w;
        { int row = tid >> 2, k2 = tid & 3;
          xIl[k2*TILE + row] = x[((size_t)b*LL + Ab + row)*4 + k2]; }

        unsigned int vO[16], vT[16];    // own (r,c) and transposed (c,r) packed state
        size_t ubA = ((size_t)b*LL + Ab)*LL + Ab;
        #pragma unroll
        for (int k = 0; k < 16; k++) {
            int r = rg + 4*k;
            float uv  = u[ubA + (size_t)r*LL + c];
            float uuv = sigm(2.0f*(uv - S_CONST))*uv;
            float ah  = sigm(uuv)*sigm(2.0f*(uuv - S_CONST));
            unsigned int p = pk2(uuv, ah);
            vO[k] = p;
            bufU[r*65 + c] = p;
        }
        if (tid < 64) rsIb[tid] = 0.0f;
        RAWBAR();
        #pragma unroll
        for (int k = 0; k < 16; k++) vT[k] = bufU[c*65 + (rg + 4*k)];

        // ---- a0 rowsums (symmetric: col sum == row sum) ----
        {
            float acc = 0.0f;
            #pragma unroll
            for (int k = 0; k < 16; k++) {
                int r = rg + 4*k;
                float ah_ij = hi2f(vO[k]), ah_ji = hi2f(vT[k]);
                float ar = xIl[0*TILE+r], ur = xIl[1*TILE+r];
                float cr = xIl[2*TILE+r], gr = xIl[3*TILE+r];
                // bitwise-symmetric m: each paren maps to itself under r<->c
                float m = (ar*uc + ac*ur) + (cr*gc + cc_*gr) + (ur*gc + uc*gr);
                acc += 0.5f*(ah_ij*ah_ij + ah_ji*ah_ji)*m;
            }
            atomicAdd(&rsIb[c], acc);
            RAWBAR();
            if (tid < 64) {
                atomicAdd(&rs[b*LL + Ab + tid], rsIb[tid]);
                asm volatile("s_waitcnt vmcnt(0)" ::: "memory");
                if (tid == 0) add_done(done, 0, b, tI);
            }
        }

        for (int t = 0; t < TT; t++) {
            LOAD_W(t);
            if (tid == 0) wait_done(&done[((size_t)t*128 + b*16 + tI)*16]);
            RAWBAR();
            const float* rs_cur = rs + (size_t)t*BB*LL;
            if (tid < 64) {
                float rsv = __hip_atomic_load(&rs_cur[b*LL + Ab + tid], __ATOMIC_RELAXED, __HIP_MEMORY_SCOPE_AGENT);
                LAM_UPDATE(rsv);
                lsI[tid] = lam * sigm(2.0f*(rsv - 1.0f));
                rsIb[tid] = 0.0f;
            }
            RAWBAR();

            size_t outBase = (((size_t)t*BB + b)*LL)*LL;
            bool last = (t == TT-1);
            float acc = 0.0f;
            #pragma unroll
            for (int k = 0; k < 16; k++) {
                int r = rg + 4*k;
                unsigned int vA = vO[k], vB = vT[k];
                float uu_ij = lo2f(vA), ah_ij = hi2f(vA);
                float uu_ji = lo2f(vB), ah_ji = hi2f(vB);
                float ar = xIl[0*TILE+r], ur = xIl[1*TILE+r];
                float cr = xIl[2*TILE+r], gr = xIl[3*TILE+r];
                float m = (ar*uc + ac*ur) + (cr*gc + cc_*gr) + (ur*gc + uc*gr);
                float lsum = lsI[r] + lsI[c];                       // symmetric grouping
                float gsum = -0.5f*(uu_ij + uu_ji) + lsum;
                float an_ij = ahnew_calc(ah_ij, ah_ij*m*gsum, uu_ij, w);
                float an_ji = ahnew_calc(ah_ji, ah_ji*m*gsum, uu_ji, w);  // mirror-owner computes same bits
                float a_val = 0.5f*(an_ij*an_ij + an_ji*an_ji)*m;
                vO[k] = ((unsigned int)f2bf(an_ij) << 16) | (vA & 0xffffu);
                vT[k] = ((unsigned int)f2bf(an_ji) << 16) | (vB & 0xffffu);
                __builtin_nontemporal_store(a_val, &out[outBase + (size_t)(Ab+r)*LL + (Ab+c)]);
                acc += a_val;
            }
            if (!last) {
                atomicAdd(&rsIb[c], acc);
                RAWBAR();
                if (tid < 64) {
                    atomicAdd(&rs[(size_t)(t+1)*BB*LL + b*LL + Ab + tid], rsIb[tid]);
                    asm volatile("s_waitcnt vmcnt(0)" ::: "memory");
                    if (tid == 0) add_done(done, t+1, b, tI);
                }
            }
        }
    }
}

extern "C" void kernel_launch(void* const* d_in, const int* in_sizes, int n_in,
                              void* d_out, int out_size, void* d_ws, size_t ws_size,
                              hipStream_t stream) {
    const float* u   = (const float*)d_in[0];
    const float* x   = (const float*)d_in[1];
    const float* aW1 = (const float*)d_in[3];
    const float* ab1 = (const float*)d_in[4];
    const float* aW2 = (const float*)d_in[5];
    const float* ab2 = (const float*)d_in[6];
    const float* rW1 = (const float*)d_in[7];
    const float* rb1 = (const float*)d_in[8];
    const float* rW2 = (const float*)d_in[9];
    const float* rb2 = (const float*)d_in[10];
    const float* lW1 = (const float*)d_in[11];
    const float* lb1 = (const float*)d_in[12];
    const float* lW2 = (const float*)d_in[13];
    const float* lb2 = (const float*)d_in[14];
    float* out = (float*)d_out;

    float* rs = (float*)d_ws;                                    // TT rowsum buffers
    unsigned int* done = (unsigned int*)(rs + (size_t)TT*BB*LL); // TT*128 padded counters
    size_t zbytes = (size_t)TT*BB*LL*sizeof(float) + (size_t)TT*128*16*sizeof(unsigned int);
    hipMemsetAsync(rs, 0, zbytes, stream);

    hipLaunchKernelGGL(k_main, dim3(NBLK), dim3(256), 0, stream,
                       u, x, rs, done, out,
                       aW1, ab1, aW2, ab2, rW1, rb1, rW2, rb2,
                       lW1, lb1, lW2, lb2);
}